// Round 9
// baseline (321.025 us; speedup 1.0000x reference)
//
#include <hip/hip_runtime.h>
#include <math.h>

// ---------------------------------------------------------------------------
// MultiheadAttention B=2,S=2048,D=1024,H=16,HD=64. I/O fp32; internal fp16 MFMA.
//   0) cvt: q,k,v,WQ..WO fp32 -> fp16, PLUS mask fp32 -> fp16*log2e
//   1) gemm_qkv: 128x128 tile, BK=64 -- R9: TWO-PHASE double-buffered LDS
//      (T3-minimum, m248v2 recipe): STAGE(next tile) issued BEFORE compute,
//      ONE vmcnt(0)+s_barrier per K-step -> tile t's compute hides tile
//      t+1's global_load_lds latency. The old structure (barrier; STAGE;
//      barrier+vmcnt0) exposed the full staging latency every K-step, and
//      at 1-3 blocks/CU (grids 256/768) no co-resident block hides it.
//   2) attn: R7 version VERBATIM (93.2 us, proven local optimum): 64-q
//      blocks, 4 blk/CU, VGPR 64, split-K x2, in-register P, pi-permuted V,
//      fp16 mask as MFMA acc-init, defer-max, lgkmcnt-only in-loop barriers.
//      R4/R5/R8 established: attn is TLP/latency-bound -- LDS-traffic
//      reduction (2-subtile, conflicts halved) LOSES when it costs blocks/CU.
//   3) gemm_o: same 2-phase pipeline -> d_out fp32
// ---------------------------------------------------------------------------

typedef _Float16 h8 __attribute__((ext_vector_type(8)));
typedef _Float16 h4 __attribute__((ext_vector_type(4)));
typedef float f4 __attribute__((ext_vector_type(4)));

#define MFMA16(a, b, c) __builtin_amdgcn_mfma_f32_16x16x32_f16((a), (b), (c), 0, 0, 0)
#define EXP2F(x) __builtin_amdgcn_exp2f(x)   // v_exp_f32 = 2^x
// Workgroup barrier WITHOUT the vmcnt(0) drain __syncthreads would emit.
#define BARRIER_LDS() asm volatile("s_waitcnt lgkmcnt(0)\n\ts_barrier" ::: "memory")
// Full drain barrier for the GEMM pipeline (one per K-step, AFTER compute).
#define BARRIER_VM0() do { \
  asm volatile("s_waitcnt vmcnt(0)" ::: "memory"); \
  __builtin_amdgcn_s_barrier(); } while (0)

static constexpr int Bn = 2, Sn = 2048, Dn = 1024, Hn = 16, HDn = 64;
static constexpr int Mn = Bn * Sn;   // 4096
static constexpr int Kn = Dn;        // 1024
static constexpr int Nn = Dn;        // 1024
static constexpr int LDP = 72;       // LDS stride (64+8 pad): 36 dwords ≡ 4 (mod 32)
static constexpr float LOG2E = 1.4426950408889634f;

__device__ __forceinline__ void gload_lds16(const _Float16* g, _Float16* l) {
  // wave-uniform LDS base; HW scatters lane i -> base + i*16 bytes [m104]
  __builtin_amdgcn_global_load_lds(
      (const __attribute__((address_space(1))) unsigned int*)g,
      (__attribute__((address_space(3))) unsigned int*)l, 16, 0, 0);
}

// ------------------------------- cvt pass ----------------------------------
struct CvtJobs {
  const float* src[8];
  _Float16* dst[8];
  int n4[8];
  float scl[8];
};

__global__ __launch_bounds__(256) void cvt_kernel(CvtJobs j) {
  const int stride = gridDim.x * blockDim.x;
  const int t0 = blockIdx.x * blockDim.x + threadIdx.x;
#pragma unroll
  for (int k = 0; k < 8; ++k) {
    const float4* __restrict__ s = (const float4*)j.src[k];
    h4* __restrict__ d = (h4*)j.dst[k];
    const int n = j.n4[k];
    const float sc = j.scl[k];
    for (int i = t0; i < n; i += stride) {
      const float4 f = s[i];
      h4 h;
      h[0] = (_Float16)(f.x * sc); h[1] = (_Float16)(f.y * sc);
      h[2] = (_Float16)(f.z * sc); h[3] = (_Float16)(f.w * sc);
      d[i] = h;
    }
  }
}

// ------------------------------- QKV GEMM ----------------------------------
struct QkvArgs {
  const _Float16* X[3];
  const _Float16* W[3];
  const float* bias[3];
  _Float16* out[3];
};

// C = X @ W^T + bias. 128x128 tile, BK=64, 4 waves 2x2, 2-phase dbuf LDS.
// z=0: Q*0.125*log2e -> [B,H,S,64]; z=1: K -> [B,H,S,64]; z=2: V^T -> [B,H,64,S]
__global__ __launch_bounds__(256) void gemm_qkv(QkvArgs args) {
  const int z = blockIdx.z;
  const _Float16* __restrict__ X = args.X[z];
  const _Float16* __restrict__ W = args.W[z];
  const float* __restrict__ bias = args.bias[z];
  _Float16* __restrict__ out = args.out[z];

  __shared__ _Float16 As[2][128 * 64];
  __shared__ _Float16 Bs[2][128 * 64];

  const int t = threadIdx.x;
  const int lane = t & 63, wv = t >> 6;
  const int l15 = lane & 15, quad = lane >> 4;
  const int wm = (wv >> 1) * 64, wn = (wv & 1) * 64;
  const int n0 = blockIdx.x * 128, m0 = blockIdx.y * 128;

  f4 acc[4][4];
#pragma unroll
  for (int i = 0; i < 4; ++i)
#pragma unroll
    for (int j = 0; j < 4; ++j) {
      f4 zz = {0.f, 0.f, 0.f, 0.f};
      acc[i][j] = zz;
    }

  const int srow = lane >> 3, scol = (lane & 7) * 8;

  auto stage = [&](int buf, int k0) {
#pragma unroll
    for (int u = 0; u < 4; ++u) {
      const int s = wv * 4 + u;
      const int row = s * 8 + srow;
      gload_lds16(X + (size_t)(m0 + row) * Kn + k0 + scol, &As[buf][s * 512]);
      gload_lds16(W + (size_t)(n0 + row) * Kn + k0 + scol, &Bs[buf][s * 512]);
    }
  };

  stage(0, 0);
  BARRIER_VM0();  // tile 0 ready

  constexpr int NKT = Kn / 64;  // 16
  for (int kt = 0; kt < NKT; ++kt) {
    const int cur = kt & 1;
    if (kt + 1 < NKT) stage(cur ^ 1, (kt + 1) * 64);  // hide under compute
#pragma unroll
    for (int kk = 0; kk < 64; kk += 32) {
      h8 af[4], bfr[4];
#pragma unroll
      for (int i = 0; i < 4; ++i)
        af[i] = *(const h8*)&As[cur][(wm + i * 16 + l15) * 64 + kk + quad * 8];
#pragma unroll
      for (int j = 0; j < 4; ++j)
        bfr[j] = *(const h8*)&Bs[cur][(wn + j * 16 + l15) * 64 + kk + quad * 8];
#pragma unroll
      for (int i = 0; i < 4; ++i)
#pragma unroll
        for (int j = 0; j < 4; ++j)
          acc[i][j] = MFMA16(af[i], bfr[j], acc[i][j]);
    }
    BARRIER_VM0();  // next tile landed; everyone done reading cur
  }

  // ---- direct-store epilogue; C/D layout col=l15, row=quad*4+r [m89/m91] ----
  const float osc = (z == 0) ? (0.125f * LOG2E) : 1.0f;
  if (z != 2) {
#pragma unroll
    for (int j = 0; j < 4; ++j) {
      const int n = n0 + wn + j * 16 + l15;
      const float bvs = bias[n] * osc;
      const int hh = n >> 6, hd = n & 63;
#pragma unroll
      for (int i = 0; i < 4; ++i) {
        const int mb = m0 + wm + i * 16 + quad * 4;
        const int bb = mb >> 11;
#pragma unroll
        for (int r = 0; r < 4; ++r) {
          const int ss = (mb + r) & (Sn - 1);
          out[(((size_t)(bb * Hn + hh)) * Sn + ss) * HDn + hd] =
              (_Float16)(acc[i][j][r] * osc + bvs);
        }
      }
    }
  } else {
#pragma unroll
    for (int j = 0; j < 4; ++j) {
      const int n = n0 + wn + j * 16 + l15;
      const float bv = bias[n];
      const int hh = n >> 6, hd = n & 63;
#pragma unroll
      for (int i = 0; i < 4; ++i) {
        const int mb = m0 + wm + i * 16 + quad * 4;
        const int bb = mb >> 11, ss = mb & (Sn - 1);
        h4 hv;
#pragma unroll
        for (int r = 0; r < 4; ++r) hv[r] = (_Float16)(acc[i][j][r] + bv);
        *(h4*)(out + (((size_t)(bb * Hn + hh)) * HDn + hd) * Sn + ss) = hv;
      }
    }
  }
}

// ------------------------------- O GEMM ------------------------------------
__global__ __launch_bounds__(256) void gemm_o(const _Float16* __restrict__ X,
                                              const _Float16* __restrict__ W,
                                              const float* __restrict__ bias,
                                              float* __restrict__ out) {
  __shared__ _Float16 As[2][128 * 64];
  __shared__ _Float16 Bs[2][128 * 64];

  const int t = threadIdx.x;
  const int lane = t & 63, wv = t >> 6;
  const int l15 = lane & 15, quad = lane >> 4;
  const int wm = (wv >> 1) * 64, wn = (wv & 1) * 64;
  const int n0 = blockIdx.x * 128, m0 = blockIdx.y * 128;

  f4 acc[4][4];
#pragma unroll
  for (int i = 0; i < 4; ++i)
#pragma unroll
    for (int j = 0; j < 4; ++j) {
      f4 zz = {0.f, 0.f, 0.f, 0.f};
      acc[i][j] = zz;
    }

  const int srow = lane >> 3, scol = (lane & 7) * 8;

  auto stage = [&](int buf, int k0) {
#pragma unroll
    for (int u = 0; u < 4; ++u) {
      const int s = wv * 4 + u;
      const int row = s * 8 + srow;
      gload_lds16(X + (size_t)(m0 + row) * Kn + k0 + scol, &As[buf][s * 512]);
      gload_lds16(W + (size_t)(n0 + row) * Kn + k0 + scol, &Bs[buf][s * 512]);
    }
  };

  stage(0, 0);
  BARRIER_VM0();

  constexpr int NKT = Kn / 64;  // 16
  for (int kt = 0; kt < NKT; ++kt) {
    const int cur = kt & 1;
    if (kt + 1 < NKT) stage(cur ^ 1, (kt + 1) * 64);
#pragma unroll
    for (int kk = 0; kk < 64; kk += 32) {
      h8 af[4], bfr[4];
#pragma unroll
      for (int i = 0; i < 4; ++i)
        af[i] = *(const h8*)&As[cur][(wm + i * 16 + l15) * 64 + kk + quad * 8];
#pragma unroll
      for (int j = 0; j < 4; ++j)
        bfr[j] = *(const h8*)&Bs[cur][(wn + j * 16 + l15) * 64 + kk + quad * 8];
#pragma unroll
      for (int i = 0; i < 4; ++i)
#pragma unroll
        for (int j = 0; j < 4; ++j)
          acc[i][j] = MFMA16(af[i], bfr[j], acc[i][j]);
    }
    BARRIER_VM0();
  }

#pragma unroll
  for (int j = 0; j < 4; ++j) {
    const int n = n0 + wn + j * 16 + l15;
    const float bv = bias[n];
#pragma unroll
    for (int i = 0; i < 4; ++i) {
      const int mb = m0 + wm + i * 16 + quad * 4;
#pragma unroll
      for (int r = 0; r < 4; ++r)
        out[(size_t)(mb + r) * Nn + n] = acc[i][j][r] + bv;
    }
  }
}

// ------------------------------ attention ----------------------------------
// R7 version verbatim (93.2 us). Transposed scores S^T = K Q^T, 512 thr =
// 8 waves, split-K x2, register-prefetch double-buffer, lgkmcnt-only
// in-loop barriers, P in-register into PV B-operand, pi-permuted V staging.
__global__ __launch_bounds__(512) void attn_kernel(
    const _Float16* __restrict__ Qh,    // [B,H,S,64], pre-scaled by 0.125*log2e
    const _Float16* __restrict__ Kh,    // [B,H,S,64]
    const _Float16* __restrict__ Vt,    // [B,H,64,S]
    const _Float16* __restrict__ maskh, // [B,S,S] fp16, pre-scaled by log2e
    _Float16* __restrict__ out) {       // [B,S,1024] fp16
  __shared__ _Float16 smem[4 * 64 * LDP];  // K0,K1,V0,V1 (padded); combine reuses

  const int t = threadIdx.x;
  const int w = t >> 6, lane = t & 63;
  const int l15 = lane & 15, quad = lane >> 4;
  const int g = w >> 2;    // key-half group
  const int wq = w & 3;    // q-subtile id (shared by pair w, w+4)

  const int bh = blockIdx.y;
  const int b = bh >> 4, h = bh & 15;
  const size_t headoff = (size_t)bh * Sn * HDn;
  const _Float16* Qp = Qh + headoff;
  const _Float16* Kp = Kh + headoff;
  const _Float16* Vp = Vt + headoff;

  const int qb = blockIdx.x * 64;
  const int q0 = qb + wq * 16;
  // Q as B-operand: n = l15 -> q, k = quad*8+j -> d
  const h8 qf0 = *(const h8*)(Qp + (size_t)(q0 + l15) * HDn + quad * 8);
  const h8 qf1 = *(const h8*)(Qp + (size_t)(q0 + l15) * HDn + 32 + quad * 8);

  const int kbase = g * (Sn / 2);
  const _Float16* mrow = maskh + ((size_t)b * Sn + q0 + l15) * Sn + kbase;

  float m_run = -INFINITY, l_part = 0.f;  // l lane-partial; quad-reduced at end
  f4 o_acc[4];
#pragma unroll
  for (int nt = 0; nt < 4; ++nt) {
    f4 zz = {0.f, 0.f, 0.f, 0.f};
    o_acc[nt] = zz;
  }

  _Float16* Kg = smem + g * (64 * LDP);
  _Float16* Vg = smem + (2 + g) * (64 * LDP);

  const int tg = t & 255;  // staging index within group (4 waves = 256 threads)
  const int srow = tg >> 3, sc8 = (tg & 7) * 8;  // K chunk geometry (row, col)
  const int srow1 = srow + 32;                   // chunk 1: same col, +32 rows
  // V permuted base: keys 8a..8a+7 land at [vb..vb+3] and [vb+8..vb+11]
  const int a = tg & 7;
  const int vb = ((a >> 2) & 1) * 32 + (a & 1) * 16 + ((a >> 1) & 1) * 4;

  constexpr int NT = (Sn / 2) / 64;  // 16 tiles per group

  // ---- register prefetch buffers ----
  uint4 kreg0, kreg1, vreg0, vreg1;
  uint2 mreg[4];
  auto kv_issue = [&](int kt) {
    kreg0 = *(const uint4*)(Kp + (size_t)(kbase + kt * 64 + srow) * HDn + sc8);
    vreg0 = *(const uint4*)(Vp + (size_t)srow * Sn + kbase + kt * 64 + sc8);
    kreg1 = *(const uint4*)(Kp + (size_t)(kbase + kt * 64 + srow1) * HDn + sc8);
    vreg1 = *(const uint4*)(Vp + (size_t)srow1 * Sn + kbase + kt * 64 + sc8);
  };
  auto m_issue = [&](int kt) {
#pragma unroll
    for (int ks = 0; ks < 4; ++ks)
      mreg[ks] = *(const uint2*)(mrow + kt * 64 + ks * 16 + quad * 4);
  };

  kv_issue(0);
  m_issue(0);

  for (int kt = 0; kt < NT; ++kt) {
    BARRIER_LDS();    // all waves done reading previous tile's LDS (no vm drain)
    // regs -> LDS (compiler emits precise vmcnt for kreg/vreg deps only)
    *(uint4*)&Kg[srow * LDP + sc8] = kreg0;
    *(uint4*)&Kg[srow1 * LDP + sc8] = kreg1;
    // V: permuted-by-pi key positions, two b64 writes per 8-key chunk
    *(uint2*)&Vg[srow * LDP + vb] = make_uint2(vreg0.x, vreg0.y);
    *(uint2*)&Vg[srow * LDP + vb + 8] = make_uint2(vreg0.z, vreg0.w);
    *(uint2*)&Vg[srow1 * LDP + vb] = make_uint2(vreg1.x, vreg1.y);
    *(uint2*)&Vg[srow1 * LDP + vb + 8] = make_uint2(vreg1.z, vreg1.w);
    BARRIER_LDS();    // tile ready (writes visible; prefetches stay in flight)
    const int nx = (kt + 1 < NT) ? kt + 1 : kt;
    kv_issue(nx);     // prefetch next tile; lands during this tile's compute

    // ---- S^T = K Q^T: rows = keys (quad*4+r), cols = q (l15) ----
    // mask (fp16, pre-scaled by log2e) enters as the MFMA accumulator init.
    f4 s[4];
#pragma unroll
    for (int ks = 0; ks < 4; ++ks) {
      const h4 mh = *(const h4*)&mreg[ks];
      f4 acc0;
#pragma unroll
      for (int r = 0; r < 4; ++r) acc0[r] = (float)mh[r];
      const h8 kf0 = *(const h8*)&Kg[(ks * 16 + l15) * LDP + quad * 8];
      const h8 kf1 = *(const h8*)&Kg[(ks * 16 + l15) * LDP + 32 + quad * 8];
      acc0 = MFMA16(kf0, qf0, acc0);
      s[ks] = MFMA16(kf1, qf1, acc0);
    }
    m_issue(nx);      // mreg consumed above; prefetch next tile's mask

    // ---- per-lane online softmax (exp2 domain); l stays lane-partial ----
    float mx = s[0][0];
#pragma unroll
    for (int ks = 0; ks < 4; ++ks)
#pragma unroll
      for (int r = 0; r < 4; ++r) mx = fmaxf(mx, s[ks][r]);
    mx = fmaxf(mx, __shfl_xor(mx, 16));
    mx = fmaxf(mx, __shfl_xor(mx, 32));
    // defer-max (T13): only rescale when the running max grows by > 8
    if (!__all(mx - m_run <= 8.0f)) {
      const float nm = fmaxf(m_run, mx);
      const float alpha = EXP2F(m_run - nm);
      m_run = nm;
      l_part *= alpha;
#pragma unroll
      for (int nt = 0; nt < 4; ++nt)
#pragma unroll
        for (int r = 0; r < 4; ++r) o_acc[nt][r] *= alpha;
    }
    float sm = 0.f;
#pragma unroll
    for (int ks = 0; ks < 4; ++ks)
#pragma unroll
      for (int r = 0; r < 4; ++r) {
        s[ks][r] = EXP2F(s[ks][r] - m_run);
        sm += s[ks][r];
      }
    l_part += sm;

    // ---- U^T += V^T P^T: P packed in-register as B-operand (no LDS) ----
#pragma unroll
    for (int c = 0; c < 2; ++c) {
      h8 pf;
#pragma unroll
      for (int r = 0; r < 4; ++r) pf[r] = (_Float16)s[2 * c][r];
#pragma unroll
      for (int r = 0; r < 4; ++r) pf[4 + r] = (_Float16)s[2 * c + 1][r];
#pragma unroll
      for (int nt = 0; nt < 4; ++nt) {
        const h8 vf = *(const h8*)&Vg[(nt * 16 + l15) * LDP + c * 32 + quad * 8];
        o_acc[nt] = MFMA16(vf, pf, o_acc[nt]);
      }
    }
  }

  // ---- quad-reduce l (deferred from the loop) ----
  l_part += __shfl_xor(l_part, 16);
  l_part += __shfl_xor(l_part, 32);

  // ---- flash combine across the two key halves (pair w <-> w+4) ----
  __syncthreads();  // full drain OK here (one-time epilogue); reuse smem fp32
  float* Uex = (float*)smem;            // [pair][q=16][stride 72] fp32
  float* mex = Uex + 4 * 16 * LDP;      // 4*16*72 = 4608 floats
  float* lex = mex + 64;
  if (g == 1) {
#pragma unroll
    for (int nt = 0; nt < 4; ++nt)
      *(f4*)&Uex[wq * 16 * LDP + l15 * LDP + nt * 16 + quad * 4] = o_acc[nt];
    if (quad == 0) {
      mex[wq * 16 + l15] = m_run;
      lex[wq * 16 + l15] = l_part;
    }
  }
  __syncthreads();
  if (g == 0) {
    const float m1 = mex[wq * 16 + l15];
    const float l1 = lex[wq * 16 + l15];
    const float mm = fmaxf(m_run, m1);
    const float f0 = EXP2F(m_run - mm);
    const float f1 = EXP2F(m1 - mm);
    const float rl = 1.0f / (f0 * l_part + f1 * l1);
    // wave-private Ob staging lives in the (now idle) V1 region
    _Float16* Ob = smem + 3 * (64 * LDP) + (w * 16) * LDP;
#pragma unroll
    for (int nt = 0; nt < 4; ++nt) {
      const f4 Ur = *(const f4*)&Uex[wq * 16 * LDP + l15 * LDP + nt * 16 + quad * 4];
      h4 ov;
#pragma unroll
      for (int r = 0; r < 4; ++r)
        ov[r] = (_Float16)((o_acc[nt][r] * f0 + Ur[r] * f1) * rl);
      *(h4*)&Ob[l15 * LDP + nt * 16 + quad * 4] = ov;  // Ob[q_local][d]
    }
    // wave-private transpose -> coalesced stores (in-wave DS ordering, R4)
    const int qr = lane >> 2;            // 0..15
    const int seg = (lane & 3) * 16;     // 0,16,32,48
    _Float16* dst = out + ((size_t)b * Sn + q0 + qr) * Dn + h * 64 + seg;
    *(uint4*)dst = *(const uint4*)&Ob[qr * LDP + seg];
    *(uint4*)(dst + 8) = *(const uint4*)&Ob[qr * LDP + seg + 8];
  }
}

// ------------------------------ launch -------------------------------------
extern "C" void kernel_launch(void* const* d_in, const int* in_sizes, int n_in,
                              void* d_out, int out_size, void* d_ws, size_t ws_size,
                              hipStream_t stream) {
  const float* q = (const float*)d_in[0];
  const float* k = (const float*)d_in[1];
  const float* v = (const float*)d_in[2];
  const float* mask = (const float*)d_in[3];
  const float* WQ = (const float*)d_in[4];
  const float* bQ = (const float*)d_in[5];
  const float* WK = (const float*)d_in[6];
  const float* bK = (const float*)d_in[7];
  const float* WV = (const float*)d_in[8];
  const float* bV = (const float*)d_in[9];
  const float* WO = (const float*)d_in[10];
  const float* bO = (const float*)d_in[11];

  _Float16* ws = (_Float16*)d_ws;
  const size_t MD = (size_t)Mn * Dn;   // 4.19M elems
  const size_t DD = (size_t)Dn * Dn;   // 1.05M
  const size_t SS = (size_t)Bn * Sn * Sn;  // 8.39M elems (mask fp16)
  _Float16* qh  = ws;
  _Float16* kh  = ws + MD;
  _Float16* vh  = ws + 2 * MD;
  _Float16* WQh = ws + 3 * MD;
  _Float16* WKh = WQh + DD;
  _Float16* WVh = WKh + DD;
  _Float16* WOh = WVh + DD;
  _Float16* Qh  = ws + 3 * MD + 4 * DD;
  _Float16* Kh  = Qh + MD;
  _Float16* Vt  = Kh + MD;
  _Float16* AO  = qh;  // qh dead after QKV gemm
  // mask fp16: prefer spare workspace after Vt; fall back to dead d_out
  const size_t used = 6 * MD + 4 * DD;
  _Float16* Mh = (ws_size >= (used + SS) * sizeof(_Float16))
                     ? (ws + used)
                     : (_Float16*)d_out;

  CvtJobs cj;
  cj.src[0] = q;    cj.dst[0] = qh;  cj.n4[0] = (int)(MD / 4);  cj.scl[0] = 1.f;
  cj.src[1] = k;    cj.dst[1] = kh;  cj.n4[1] = (int)(MD / 4);  cj.scl[1] = 1.f;
  cj.src[2] = v;    cj.dst[2] = vh;  cj.n4[2] = (int)(MD / 4);  cj.scl[2] = 1.f;
  cj.src[3] = WQ;   cj.dst[3] = WQh; cj.n4[3] = (int)(DD / 4);  cj.scl[3] = 1.f;
  cj.src[4] = WK;   cj.dst[4] = WKh; cj.n4[4] = (int)(DD / 4);  cj.scl[4] = 1.f;
  cj.src[5] = WV;   cj.dst[5] = WVh; cj.n4[5] = (int)(DD / 4);  cj.scl[5] = 1.f;
  cj.src[6] = WO;   cj.dst[6] = WOh; cj.n4[6] = (int)(DD / 4);  cj.scl[6] = 1.f;
  cj.src[7] = mask; cj.dst[7] = Mh;  cj.n4[7] = (int)(SS / 4);  cj.scl[7] = LOG2E;
  cvt_kernel<<<1024, 256, 0, stream>>>(cj);

  QkvArgs ga;
  ga.X[0] = qh; ga.W[0] = WQh; ga.bias[0] = bQ; ga.out[0] = Qh;
  ga.X[1] = kh; ga.W[1] = WKh; ga.bias[1] = bK; ga.out[1] = Kh;
  ga.X[2] = vh; ga.W[2] = WVh; ga.bias[2] = bV; ga.out[2] = Vt;
  gemm_qkv<<<dim3(Nn / 128, Mn / 128, 3), 256, 0, stream>>>(ga);

  attn_kernel<<<dim3(Sn / 64, Bn * Hn), 512, 0, stream>>>(Qh, Kh, Vt, Mh, AO);

  gemm_o<<<dim3(Nn / 128, Mn / 128), 256, 0, stream>>>(AO, WOh, bO, (float*)d_out);
}

// Round 10
// 296.682 us; speedup vs baseline: 1.0821x; 1.0821x over previous
//
#include <hip/hip_runtime.h>
#include <math.h>

// ---------------------------------------------------------------------------
// MultiheadAttention B=2,S=2048,D=1024,H=16,HD=64. I/O fp32; internal fp16 MFMA.
//   0) cvt: q,k,v,WQ..WO fp32 -> fp16, PLUS mask fp32 -> fp16*log2e
//   1) gemm_qkv: R10 retile 64x128 (BM=64,BN=128,BK=64, 256 thr, single-buf
//      LDS 24KB) -> grid 1536 = 6 blocks/CU fully resident. R9's 2-phase
//      dbuf regressed (-20us): 64KB LDS halved occupancy; GEMMs are
//      TLP-bound (m102 shape-curve: ~300 TF at grid<=768, 833 at 1024+),
//      so more blocks beats deeper pipeline. Wave decomposition is a strict
//      specialization of the validated 128x128 kernel (wm=0, wn=w*32).
//   2) attn: R7 version VERBATIM (92-93 us local optimum): 64-q blocks,
//      4 blk/CU, VGPR 64, split-K x2, in-register P, pi-permuted V, fp16
//      mask as MFMA acc-init, defer-max, lgkmcnt-only in-loop barriers.
//   3) gemm_o: same 64x128 retile -> grid 512 = 2 blocks/CU (was 1).
// ---------------------------------------------------------------------------

typedef _Float16 h8 __attribute__((ext_vector_type(8)));
typedef _Float16 h4 __attribute__((ext_vector_type(4)));
typedef float f4 __attribute__((ext_vector_type(4)));

#define MFMA16(a, b, c) __builtin_amdgcn_mfma_f32_16x16x32_f16((a), (b), (c), 0, 0, 0)
#define EXP2F(x) __builtin_amdgcn_exp2f(x)   // v_exp_f32 = 2^x
// Workgroup barrier WITHOUT the vmcnt(0) drain __syncthreads would emit.
#define BARRIER_LDS() asm volatile("s_waitcnt lgkmcnt(0)\n\ts_barrier" ::: "memory")

static constexpr int Bn = 2, Sn = 2048, Dn = 1024, Hn = 16, HDn = 64;
static constexpr int Mn = Bn * Sn;   // 4096
static constexpr int Kn = Dn;        // 1024
static constexpr int Nn = Dn;        // 1024
static constexpr int LDP = 72;       // LDS stride (64+8 pad): 36 dwords ≡ 4 (mod 32)
static constexpr float LOG2E = 1.4426950408889634f;

__device__ __forceinline__ void gload_lds16(const _Float16* g, _Float16* l) {
  // wave-uniform LDS base; HW scatters lane i -> base + i*16 bytes [m104]
  __builtin_amdgcn_global_load_lds(
      (const __attribute__((address_space(1))) unsigned int*)g,
      (__attribute__((address_space(3))) unsigned int*)l, 16, 0, 0);
}

// ------------------------------- cvt pass ----------------------------------
struct CvtJobs {
  const float* src[8];
  _Float16* dst[8];
  int n4[8];
  float scl[8];
};

__global__ __launch_bounds__(256) void cvt_kernel(CvtJobs j) {
  const int stride = gridDim.x * blockDim.x;
  const int t0 = blockIdx.x * blockDim.x + threadIdx.x;
#pragma unroll
  for (int k = 0; k < 8; ++k) {
    const float4* __restrict__ s = (const float4*)j.src[k];
    h4* __restrict__ d = (h4*)j.dst[k];
    const int n = j.n4[k];
    const float sc = j.scl[k];
    for (int i = t0; i < n; i += stride) {
      const float4 f = s[i];
      h4 h;
      h[0] = (_Float16)(f.x * sc); h[1] = (_Float16)(f.y * sc);
      h[2] = (_Float16)(f.z * sc); h[3] = (_Float16)(f.w * sc);
      d[i] = h;
    }
  }
}

// ------------------------------- QKV GEMM ----------------------------------
struct QkvArgs {
  const _Float16* X[3];
  const _Float16* W[3];
  const float* bias[3];
  _Float16* out[3];
};

// C = X @ W^T + bias. 64x128 tile, BK=64, 4 waves (wave w: all 64 rows x
// cols [w*32, w*32+32)), single-buffered LDS (24 KB), m97 gload_lds staging.
// z=0: Q*0.125*log2e -> [B,H,S,64]; z=1: K -> [B,H,S,64]; z=2: V^T -> [B,H,64,S]
__global__ __launch_bounds__(256) void gemm_qkv(QkvArgs args) {
  const int z = blockIdx.z;
  const _Float16* __restrict__ X = args.X[z];
  const _Float16* __restrict__ W = args.W[z];
  const float* __restrict__ bias = args.bias[z];
  _Float16* __restrict__ out = args.out[z];

  __shared__ _Float16 As[64 * 64];    // 8 KB
  __shared__ _Float16 Bs[128 * 64];   // 16 KB

  const int t = threadIdx.x;
  const int lane = t & 63, wv = t >> 6;
  const int l15 = lane & 15, quad = lane >> 4;
  const int wn = wv * 32;
  const int n0 = blockIdx.x * 128, m0 = blockIdx.y * 64;

  f4 acc[4][2];
#pragma unroll
  for (int i = 0; i < 4; ++i)
#pragma unroll
    for (int j = 0; j < 2; ++j) {
      f4 zz = {0.f, 0.f, 0.f, 0.f};
      acc[i][j] = zz;
    }

  const int srow = lane >> 3, scol = (lane & 7) * 8;

  for (int k0 = 0; k0 < Kn; k0 += 64) {
    __syncthreads();
#pragma unroll
    for (int u = 0; u < 2; ++u) {     // A: 64 rows = 8 s-slices
      const int s = wv * 2 + u;
      const int row = s * 8 + srow;
      gload_lds16(X + (size_t)(m0 + row) * Kn + k0 + scol, As + s * 512);
    }
#pragma unroll
    for (int u = 0; u < 4; ++u) {     // B: 128 rows = 16 s-slices
      const int s = wv * 4 + u;
      const int row = s * 8 + srow;
      gload_lds16(W + (size_t)(n0 + row) * Kn + k0 + scol, Bs + s * 512);
    }
    __syncthreads();
#pragma unroll
    for (int kk = 0; kk < 64; kk += 32) {
      h8 af[4], bfr[2];
#pragma unroll
      for (int i = 0; i < 4; ++i)
        af[i] = *(const h8*)&As[(i * 16 + l15) * 64 + kk + quad * 8];
#pragma unroll
      for (int j = 0; j < 2; ++j)
        bfr[j] = *(const h8*)&Bs[(wn + j * 16 + l15) * 64 + kk + quad * 8];
#pragma unroll
      for (int i = 0; i < 4; ++i)
#pragma unroll
        for (int j = 0; j < 2; ++j)
          acc[i][j] = MFMA16(af[i], bfr[j], acc[i][j]);
    }
  }

  // ---- direct-store epilogue; C/D layout col=l15, row=quad*4+r [m89/m91] ----
  const float osc = (z == 0) ? (0.125f * LOG2E) : 1.0f;
  if (z != 2) {
#pragma unroll
    for (int j = 0; j < 2; ++j) {
      const int n = n0 + wn + j * 16 + l15;
      const float bvs = bias[n] * osc;
      const int hh = n >> 6, hd = n & 63;
#pragma unroll
      for (int i = 0; i < 4; ++i) {
        const int mb = m0 + i * 16 + quad * 4;
        const int bb = mb >> 11;
#pragma unroll
        for (int r = 0; r < 4; ++r) {
          const int ss = (mb + r) & (Sn - 1);
          out[(((size_t)(bb * Hn + hh)) * Sn + ss) * HDn + hd] =
              (_Float16)(acc[i][j][r] * osc + bvs);
        }
      }
    }
  } else {
#pragma unroll
    for (int j = 0; j < 2; ++j) {
      const int n = n0 + wn + j * 16 + l15;
      const float bv = bias[n];
      const int hh = n >> 6, hd = n & 63;
#pragma unroll
      for (int i = 0; i < 4; ++i) {
        const int mb = m0 + i * 16 + quad * 4;
        const int bb = mb >> 11, ss = mb & (Sn - 1);
        h4 hv;
#pragma unroll
        for (int r = 0; r < 4; ++r) hv[r] = (_Float16)(acc[i][j][r] + bv);
        *(h4*)(out + (((size_t)(bb * Hn + hh)) * HDn + hd) * Sn + ss) = hv;
      }
    }
  }
}

// ------------------------------- O GEMM ------------------------------------
// Same 64x128 tile -> grid 512 = 2 blocks/CU (was 1 at 128x128).
__global__ __launch_bounds__(256) void gemm_o(const _Float16* __restrict__ X,
                                              const _Float16* __restrict__ W,
                                              const float* __restrict__ bias,
                                              float* __restrict__ out) {
  __shared__ _Float16 As[64 * 64];
  __shared__ _Float16 Bs[128 * 64];

  const int t = threadIdx.x;
  const int lane = t & 63, wv = t >> 6;
  const int l15 = lane & 15, quad = lane >> 4;
  const int wn = wv * 32;
  const int n0 = blockIdx.x * 128, m0 = blockIdx.y * 64;

  f4 acc[4][2];
#pragma unroll
  for (int i = 0; i < 4; ++i)
#pragma unroll
    for (int j = 0; j < 2; ++j) {
      f4 zz = {0.f, 0.f, 0.f, 0.f};
      acc[i][j] = zz;
    }

  const int srow = lane >> 3, scol = (lane & 7) * 8;

  for (int k0 = 0; k0 < Kn; k0 += 64) {
    __syncthreads();
#pragma unroll
    for (int u = 0; u < 2; ++u) {
      const int s = wv * 2 + u;
      const int row = s * 8 + srow;
      gload_lds16(X + (size_t)(m0 + row) * Kn + k0 + scol, As + s * 512);
    }
#pragma unroll
    for (int u = 0; u < 4; ++u) {
      const int s = wv * 4 + u;
      const int row = s * 8 + srow;
      gload_lds16(W + (size_t)(n0 + row) * Kn + k0 + scol, Bs + s * 512);
    }
    __syncthreads();
#pragma unroll
    for (int kk = 0; kk < 64; kk += 32) {
      h8 af[4], bfr[2];
#pragma unroll
      for (int i = 0; i < 4; ++i)
        af[i] = *(const h8*)&As[(i * 16 + l15) * 64 + kk + quad * 8];
#pragma unroll
      for (int j = 0; j < 2; ++j)
        bfr[j] = *(const h8*)&Bs[(wn + j * 16 + l15) * 64 + kk + quad * 8];
#pragma unroll
      for (int i = 0; i < 4; ++i)
#pragma unroll
        for (int j = 0; j < 2; ++j)
          acc[i][j] = MFMA16(af[i], bfr[j], acc[i][j]);
    }
  }

#pragma unroll
  for (int j = 0; j < 2; ++j) {
    const int n = n0 + wn + j * 16 + l15;
    const float bv = bias[n];
#pragma unroll
    for (int i = 0; i < 4; ++i) {
      const int mb = m0 + i * 16 + quad * 4;
#pragma unroll
      for (int r = 0; r < 4; ++r)
        out[(size_t)(mb + r) * Nn + n] = acc[i][j][r] + bv;
    }
  }
}

// ------------------------------ attention ----------------------------------
// R7 version verbatim (92-93 us). Transposed scores S^T = K Q^T, 512 thr =
// 8 waves, split-K x2, register-prefetch double-buffer, lgkmcnt-only
// in-loop barriers, P in-register into PV B-operand, pi-permuted V staging.
__global__ __launch_bounds__(512) void attn_kernel(
    const _Float16* __restrict__ Qh,    // [B,H,S,64], pre-scaled by 0.125*log2e
    const _Float16* __restrict__ Kh,    // [B,H,S,64]
    const _Float16* __restrict__ Vt,    // [B,H,64,S]
    const _Float16* __restrict__ maskh, // [B,S,S] fp16, pre-scaled by log2e
    _Float16* __restrict__ out) {       // [B,S,1024] fp16
  __shared__ _Float16 smem[4 * 64 * LDP];  // K0,K1,V0,V1 (padded); combine reuses

  const int t = threadIdx.x;
  const int w = t >> 6, lane = t & 63;
  const int l15 = lane & 15, quad = lane >> 4;
  const int g = w >> 2;    // key-half group
  const int wq = w & 3;    // q-subtile id (shared by pair w, w+4)

  const int bh = blockIdx.y;
  const int b = bh >> 4, h = bh & 15;
  const size_t headoff = (size_t)bh * Sn * HDn;
  const _Float16* Qp = Qh + headoff;
  const _Float16* Kp = Kh + headoff;
  const _Float16* Vp = Vt + headoff;

  const int qb = blockIdx.x * 64;
  const int q0 = qb + wq * 16;
  // Q as B-operand: n = l15 -> q, k = quad*8+j -> d
  const h8 qf0 = *(const h8*)(Qp + (size_t)(q0 + l15) * HDn + quad * 8);
  const h8 qf1 = *(const h8*)(Qp + (size_t)(q0 + l15) * HDn + 32 + quad * 8);

  const int kbase = g * (Sn / 2);
  const _Float16* mrow = maskh + ((size_t)b * Sn + q0 + l15) * Sn + kbase;

  float m_run = -INFINITY, l_part = 0.f;  // l lane-partial; quad-reduced at end
  f4 o_acc[4];
#pragma unroll
  for (int nt = 0; nt < 4; ++nt) {
    f4 zz = {0.f, 0.f, 0.f, 0.f};
    o_acc[nt] = zz;
  }

  _Float16* Kg = smem + g * (64 * LDP);
  _Float16* Vg = smem + (2 + g) * (64 * LDP);

  const int tg = t & 255;  // staging index within group (4 waves = 256 threads)
  const int srow = tg >> 3, sc8 = (tg & 7) * 8;  // K chunk geometry (row, col)
  const int srow1 = srow + 32;                   // chunk 1: same col, +32 rows
  // V permuted base: keys 8a..8a+7 land at [vb..vb+3] and [vb+8..vb+11]
  const int a = tg & 7;
  const int vb = ((a >> 2) & 1) * 32 + (a & 1) * 16 + ((a >> 1) & 1) * 4;

  constexpr int NT = (Sn / 2) / 64;  // 16 tiles per group

  // ---- register prefetch buffers ----
  uint4 kreg0, kreg1, vreg0, vreg1;
  uint2 mreg[4];
  auto kv_issue = [&](int kt) {
    kreg0 = *(const uint4*)(Kp + (size_t)(kbase + kt * 64 + srow) * HDn + sc8);
    vreg0 = *(const uint4*)(Vp + (size_t)srow * Sn + kbase + kt * 64 + sc8);
    kreg1 = *(const uint4*)(Kp + (size_t)(kbase + kt * 64 + srow1) * HDn + sc8);
    vreg1 = *(const uint4*)(Vp + (size_t)srow1 * Sn + kbase + kt * 64 + sc8);
  };
  auto m_issue = [&](int kt) {
#pragma unroll
    for (int ks = 0; ks < 4; ++ks)
      mreg[ks] = *(const uint2*)(mrow + kt * 64 + ks * 16 + quad * 4);
  };

  kv_issue(0);
  m_issue(0);

  for (int kt = 0; kt < NT; ++kt) {
    BARRIER_LDS();    // all waves done reading previous tile's LDS (no vm drain)
    // regs -> LDS (compiler emits precise vmcnt for kreg/vreg deps only)
    *(uint4*)&Kg[srow * LDP + sc8] = kreg0;
    *(uint4*)&Kg[srow1 * LDP + sc8] = kreg1;
    // V: permuted-by-pi key positions, two b64 writes per 8-key chunk
    *(uint2*)&Vg[srow * LDP + vb] = make_uint2(vreg0.x, vreg0.y);
    *(uint2*)&Vg[srow * LDP + vb + 8] = make_uint2(vreg0.z, vreg0.w);
    *(uint2*)&Vg[srow1 * LDP + vb] = make_uint2(vreg1.x, vreg1.y);
    *(uint2*)&Vg[srow1 * LDP + vb + 8] = make_uint2(vreg1.z, vreg1.w);
    BARRIER_LDS();    // tile ready (writes visible; prefetches stay in flight)
    const int nx = (kt + 1 < NT) ? kt + 1 : kt;
    kv_issue(nx);     // prefetch next tile; lands during this tile's compute

    // ---- S^T = K Q^T: rows = keys (quad*4+r), cols = q (l15) ----
    // mask (fp16, pre-scaled by log2e) enters as the MFMA accumulator init.
    f4 s[4];
#pragma unroll
    for (int ks = 0; ks < 4; ++ks) {
      const h4 mh = *(const h4*)&mreg[ks];
      f4 acc0;
#pragma unroll
      for (int r = 0; r < 4; ++r) acc0[r] = (float)mh[r];
      const h8 kf0 = *(const h8*)&Kg[(ks * 16 + l15) * LDP + quad * 8];
      const h8 kf1 = *(const h8*)&Kg[(ks * 16 + l15) * LDP + 32 + quad * 8];
      acc0 = MFMA16(kf0, qf0, acc0);
      s[ks] = MFMA16(kf1, qf1, acc0);
    }
    m_issue(nx);      // mreg consumed above; prefetch next tile's mask

    // ---- per-lane online softmax (exp2 domain); l stays lane-partial ----
    float mx = s[0][0];
#pragma unroll
    for (int ks = 0; ks < 4; ++ks)
#pragma unroll
      for (int r = 0; r < 4; ++r) mx = fmaxf(mx, s[ks][r]);
    mx = fmaxf(mx, __shfl_xor(mx, 16));
    mx = fmaxf(mx, __shfl_xor(mx, 32));
    // defer-max (T13): only rescale when the running max grows by > 8
    if (!__all(mx - m_run <= 8.0f)) {
      const float nm = fmaxf(m_run, mx);
      const float alpha = EXP2F(m_run - nm);
      m_run = nm;
      l_part *= alpha;
#pragma unroll
      for (int nt = 0; nt < 4; ++nt)
#pragma unroll
        for (int r = 0; r < 4; ++r) o_acc[nt][r] *= alpha;
    }
    float sm = 0.f;
#pragma unroll
    for (int ks = 0; ks < 4; ++ks)
#pragma unroll
      for (int r = 0; r < 4; ++r) {
        s[ks][r] = EXP2F(s[ks][r] - m_run);
        sm += s[ks][r];
      }
    l_part += sm;

    // ---- U^T += V^T P^T: P packed in-register as B-operand (no LDS) ----
#pragma unroll
    for (int c = 0; c < 2; ++c) {
      h8 pf;
#pragma unroll
      for (int r = 0; r < 4; ++r) pf[r] = (_Float16)s[2 * c][r];
#pragma unroll
      for (int r = 0; r < 4; ++r) pf[4 + r] = (_Float16)s[2 * c + 1][r];
#pragma unroll
      for (int nt = 0; nt < 4; ++nt) {
        const h8 vf = *(const h8*)&Vg[(nt * 16 + l15) * LDP + c * 32 + quad * 8];
        o_acc[nt] = MFMA16(vf, pf, o_acc[nt]);
      }
    }
  }

  // ---- quad-reduce l (deferred from the loop) ----
  l_part += __shfl_xor(l_part, 16);
  l_part += __shfl_xor(l_part, 32);

  // ---- flash combine across the two key halves (pair w <-> w+4) ----
  __syncthreads();  // full drain OK here (one-time epilogue); reuse smem fp32
  float* Uex = (float*)smem;            // [pair][q=16][stride 72] fp32
  float* mex = Uex + 4 * 16 * LDP;      // 4*16*72 = 4608 floats
  float* lex = mex + 64;
  if (g == 1) {
#pragma unroll
    for (int nt = 0; nt < 4; ++nt)
      *(f4*)&Uex[wq * 16 * LDP + l15 * LDP + nt * 16 + quad * 4] = o_acc[nt];
    if (quad == 0) {
      mex[wq * 16 + l15] = m_run;
      lex[wq * 16 + l15] = l_part;
    }
  }
  __syncthreads();
  if (g == 0) {
    const float m1 = mex[wq * 16 + l15];
    const float l1 = lex[wq * 16 + l15];
    const float mm = fmaxf(m_run, m1);
    const float f0 = EXP2F(m_run - mm);
    const float f1 = EXP2F(m1 - mm);
    const float rl = 1.0f / (f0 * l_part + f1 * l1);
    // wave-private Ob staging lives in the (now idle) V1 region
    _Float16* Ob = smem + 3 * (64 * LDP) + (w * 16) * LDP;
#pragma unroll
    for (int nt = 0; nt < 4; ++nt) {
      const f4 Ur = *(const f4*)&Uex[wq * 16 * LDP + l15 * LDP + nt * 16 + quad * 4];
      h4 ov;
#pragma unroll
      for (int r = 0; r < 4; ++r)
        ov[r] = (_Float16)((o_acc[nt][r] * f0 + Ur[r] * f1) * rl);
      *(h4*)&Ob[l15 * LDP + nt * 16 + quad * 4] = ov;  // Ob[q_local][d]
    }
    // wave-private transpose -> coalesced stores (in-wave DS ordering, R4)
    const int qr = lane >> 2;            // 0..15
    const int seg = (lane & 3) * 16;     // 0,16,32,48
    _Float16* dst = out + ((size_t)b * Sn + q0 + qr) * Dn + h * 64 + seg;
    *(uint4*)dst = *(const uint4*)&Ob[qr * LDP + seg];
    *(uint4*)(dst + 8) = *(const uint4*)&Ob[qr * LDP + seg + 8];
  }
}

// ------------------------------ launch -------------------------------------
extern "C" void kernel_launch(void* const* d_in, const int* in_sizes, int n_in,
                              void* d_out, int out_size, void* d_ws, size_t ws_size,
                              hipStream_t stream) {
  const float* q = (const float*)d_in[0];
  const float* k = (const float*)d_in[1];
  const float* v = (const float*)d_in[2];
  const float* mask = (const float*)d_in[3];
  const float* WQ = (const float*)d_in[4];
  const float* bQ = (const float*)d_in[5];
  const float* WK = (const float*)d_in[6];
  const float* bK = (const float*)d_in[7];
  const float* WV = (const float*)d_in[8];
  const float* bV = (const float*)d_in[9];
  const float* WO = (const float*)d_in[10];
  const float* bO = (const float*)d_in[11];

  _Float16* ws = (_Float16*)d_ws;
  const size_t MD = (size_t)Mn * Dn;   // 4.19M elems
  const size_t DD = (size_t)Dn * Dn;   // 1.05M
  const size_t SS = (size_t)Bn * Sn * Sn;  // 8.39M elems (mask fp16)
  _Float16* qh  = ws;
  _Float16* kh  = ws + MD;
  _Float16* vh  = ws + 2 * MD;
  _Float16* WQh = ws + 3 * MD;
  _Float16* WKh = WQh + DD;
  _Float16* WVh = WKh + DD;
  _Float16* WOh = WVh + DD;
  _Float16* Qh  = ws + 3 * MD + 4 * DD;
  _Float16* Kh  = Qh + MD;
  _Float16* Vt  = Kh + MD;
  _Float16* AO  = qh;  // qh dead after QKV gemm
  // mask fp16: prefer spare workspace after Vt; fall back to dead d_out
  const size_t used = 6 * MD + 4 * DD;
  _Float16* Mh = (ws_size >= (used + SS) * sizeof(_Float16))
                     ? (ws + used)
                     : (_Float16*)d_out;

  CvtJobs cj;
  cj.src[0] = q;    cj.dst[0] = qh;  cj.n4[0] = (int)(MD / 4);  cj.scl[0] = 1.f;
  cj.src[1] = k;    cj.dst[1] = kh;  cj.n4[1] = (int)(MD / 4);  cj.scl[1] = 1.f;
  cj.src[2] = v;    cj.dst[2] = vh;  cj.n4[2] = (int)(MD / 4);  cj.scl[2] = 1.f;
  cj.src[3] = WQ;   cj.dst[3] = WQh; cj.n4[3] = (int)(DD / 4);  cj.scl[3] = 1.f;
  cj.src[4] = WK;   cj.dst[4] = WKh; cj.n4[4] = (int)(DD / 4);  cj.scl[4] = 1.f;
  cj.src[5] = WV;   cj.dst[5] = WVh; cj.n4[5] = (int)(DD / 4);  cj.scl[5] = 1.f;
  cj.src[6] = WO;   cj.dst[6] = WOh; cj.n4[6] = (int)(DD / 4);  cj.scl[6] = 1.f;
  cj.src[7] = mask; cj.dst[7] = Mh;  cj.n4[7] = (int)(SS / 4);  cj.scl[7] = LOG2E;
  cvt_kernel<<<1024, 256, 0, stream>>>(cj);

  QkvArgs ga;
  ga.X[0] = qh; ga.W[0] = WQh; ga.bias[0] = bQ; ga.out[0] = Qh;
  ga.X[1] = kh; ga.W[1] = WKh; ga.bias[1] = bK; ga.out[1] = Kh;
  ga.X[2] = vh; ga.W[2] = WVh; ga.bias[2] = bV; ga.out[2] = Vt;
  gemm_qkv<<<dim3(Nn / 128, Mn / 64, 3), 256, 0, stream>>>(ga);

  attn_kernel<<<dim3(Sn / 64, Bn * Hn), 512, 0, stream>>>(Qh, Kh, Vt, Mh, AO);

  gemm_o<<<dim3(Nn / 128, Mn / 64), 256, 0, stream>>>(AO, WOh, bO, (float*)d_out);
}